// Round 5
// baseline (1007.496 us; speedup 1.0000x reference)
//
#include <hip/hip_runtime.h>
#include <math.h>

typedef __attribute__((ext_vector_type(8))) short s16x8;   // 8 bf16 (4 VGPRs)
typedef __attribute__((ext_vector_type(4))) float f32x4;

__device__ inline ushort f2bf(float f) {
    union { float f; unsigned u; } v; v.f = f;
    unsigned r = v.u + 0x7FFF + ((v.u >> 16) & 1);   // RTN-even
    return (ushort)(r >> 16);
}
__device__ inline float bf2f(ushort h) {
    union { unsigned u; float f; } v; v.u = ((unsigned)h) << 16;
    return v.f;
}
__device__ inline float bfLo(unsigned u) {
    union { unsigned x; float f; } v; v.x = u << 16; return v.f;
}
__device__ inline float bfHi(unsigned u) {
    union { unsigned x; float f; } v; v.x = u & 0xFFFF0000u; return v.f;
}
__device__ inline unsigned pk(float a, float b) {   // pack 2 bf16
    return (unsigned)f2bf(a) | ((unsigned)f2bf(b) << 16);
}

// ---------------- CSR build ----------------

__global__ void hist_kernel(const int* __restrict__ dst, int E, int* __restrict__ cnt) {
    int e = blockIdx.x * blockDim.x + threadIdx.x;
    if (e < E) atomicAdd(&cnt[dst[e]], 1);
}

__global__ void alloc_kernel(const int* __restrict__ cnt, int* __restrict__ row_start,
                             float* __restrict__ dinv, int* __restrict__ total, int N) {
    int i = blockIdx.x * blockDim.x + threadIdx.x;
    int lane = threadIdx.x & 63;
    int c = (i < N) ? cnt[i] : 0;
    int inc = c;
#pragma unroll
    for (int o = 1; o < 64; o <<= 1) {
        int v = __shfl_up(inc, o, 64);
        if (lane >= o) inc += v;
    }
    int wsum = __shfl(inc, 63, 64);
    int base = 0;
    if (lane == 0) base = atomicAdd(total, wsum);
    base = __shfl(base, 0, 64);
    if (i < N) {
        row_start[i] = base + inc - c;
        dinv[i] = rsqrtf((float)(c + 1));
    }
}

__global__ void scatter_kernel(const int* __restrict__ src, const int* __restrict__ dst, int E,
                               const int* __restrict__ row_start, int* __restrict__ cursor,
                               int* __restrict__ csr) {
    int e = blockIdx.x * blockDim.x + threadIdx.x;
    if (e < E) {
        int d = dst[e];
        int p = row_start[d] + atomicAdd(&cursor[d], 1);
        csr[p] = src[e];
    }
}

// ---------------- W1^T hi/lo split precompute: wt[n][k] bf16 ----------------
__global__ void wsplit_kernel(const float* __restrict__ W, ushort* __restrict__ wt_hi,
                              ushort* __restrict__ wt_lo) {
    int idx = blockIdx.x * blockDim.x + threadIdx.x;
    if (idx < 64 * 512) {
        int n = idx & 63, k = idx >> 6;
        float f = W[k * 64 + n];
        ushort h = f2bf(f);
        wt_hi[n * 512 + k] = h;
        wt_lo[n * 512 + k] = f2bf(f - bf2f(h));
    }
}

// ---------------- GEMM1 (MFMA): p = dinv * (x @ W1) as bf16, hi/lo 3-term split ----------
__global__ __launch_bounds__(256, 3) void gemm1_kernel(const float* __restrict__ x,
                                                       const ushort* __restrict__ wt_hi,
                                                       const ushort* __restrict__ wt_lo,
                                                       const float* __restrict__ dinv,
                                                       ushort* __restrict__ out, int N) {
    __shared__ __align__(16) short xs_hi[128 * 64];
    __shared__ __align__(16) short xs_lo[128 * 64];
    __shared__ __align__(16) short ws_hi[64 * 64];
    __shared__ __align__(16) short ws_lo[64 * 64];

    const int tid = threadIdx.x;
    const int nodeBase = blockIdx.x * 128;
    const int wave = tid >> 6, lane = tid & 63;
    const int m16 = lane & 15, quad = lane >> 4;

    f32x4 acc[2][4];
#pragma unroll
    for (int mt = 0; mt < 2; mt++)
#pragma unroll
        for (int nt = 0; nt < 4; nt++) acc[mt][nt] = (f32x4){0.f, 0.f, 0.f, 0.f};

    for (int kc = 0; kc < 512; kc += 64) {
        __syncthreads();
#pragma unroll
        for (int i = 0; i < 4; i++) {
            int f = tid + i * 256;
            int node = f >> 3, g = f & 7;
            int gn = nodeBase + node;
            if (gn >= N) gn = N - 1;
            const float4 a = *(const float4*)(x + (size_t)gn * 512 + kc + g * 8);
            const float4 b = *(const float4*)(x + (size_t)gn * 512 + kc + g * 8 + 4);
            float ff[8] = {a.x, a.y, a.z, a.w, b.x, b.y, b.z, b.w};
            union { ushort u[8]; uint4 v; } H, L;
#pragma unroll
            for (int j = 0; j < 8; j++) {
                ushort h = f2bf(ff[j]);
                H.u[j] = h;
                L.u[j] = f2bf(ff[j] - bf2f(h));
            }
            int gp = (g + node) & 7;
            *(uint4*)&xs_hi[node * 64 + gp * 8] = H.v;
            *(uint4*)&xs_lo[node * 64 + gp * 8] = L.v;
        }
#pragma unroll
        for (int i = 0; i < 2; i++) {
            int f = tid + i * 256;
            int n = f >> 3, g = f & 7;
            int gp = (g + n) & 7;
            *(uint4*)&ws_hi[n * 64 + gp * 8] =
                *(const uint4*)(wt_hi + (size_t)n * 512 + kc + g * 8);
            *(uint4*)&ws_lo[n * 64 + gp * 8] =
                *(const uint4*)(wt_lo + (size_t)n * 512 + kc + g * 8);
        }
        __syncthreads();
#pragma unroll
        for (int ck = 0; ck < 2; ck++) {
            s16x8 Ah[2], Al[2];
#pragma unroll
            for (int mt = 0; mt < 2; mt++) {
                int row = (wave * 2 + mt) * 16 + m16;
                int gp = (ck * 4 + quad + row) & 7;
                Ah[mt] = *(s16x8*)&xs_hi[row * 64 + gp * 8];
                Al[mt] = *(s16x8*)&xs_lo[row * 64 + gp * 8];
            }
#pragma unroll
            for (int nt = 0; nt < 4; nt++) {
                int n = nt * 16 + m16;
                int gp = (ck * 4 + quad + n) & 7;
                s16x8 Bh = *(s16x8*)&ws_hi[n * 64 + gp * 8];
                s16x8 Bl = *(s16x8*)&ws_lo[n * 64 + gp * 8];
#pragma unroll
                for (int mt = 0; mt < 2; mt++) {
                    acc[mt][nt] = __builtin_amdgcn_mfma_f32_16x16x32_bf16(Ah[mt], Bh, acc[mt][nt], 0, 0, 0);
                    acc[mt][nt] = __builtin_amdgcn_mfma_f32_16x16x32_bf16(Ah[mt], Bl, acc[mt][nt], 0, 0, 0);
                    acc[mt][nt] = __builtin_amdgcn_mfma_f32_16x16x32_bf16(Al[mt], Bh, acc[mt][nt], 0, 0, 0);
                }
            }
        }
    }
#pragma unroll
    for (int mt = 0; mt < 2; mt++) {
#pragma unroll
        for (int r = 0; r < 4; r++) {
            int gn = nodeBase + (wave * 2 + mt) * 16 + quad * 4 + r;
            if (gn < N) {
                float di = dinv[gn];
#pragma unroll
                for (int nt = 0; nt < 4; nt++)
                    out[(size_t)gn * 64 + nt * 16 + m16] = f2bf(di * acc[mt][nt][r]);
            }
        }
    }
}

// ---------------- 64-dim CSR aggregation, 8 edges per vmem instruction ----------------
// Wave = one node. Lane (e8,f8): e8=lane>>3 edge slot, f8=lane&7 feature group.
// One b128 gather covers 8 full edge rows (1 KB). Cross-slot reduce: shfl 32/16/8.
template <int RELU, int BIAS, int PREMUL>
__global__ void agg64bf_kernel(const ushort* __restrict__ in, ushort* __restrict__ out,
                               const int* __restrict__ row_start, const int* __restrict__ cnt,
                               const int* __restrict__ csr, const float* __restrict__ dinv,
                               const float* __restrict__ bias, int N) {
    int gw = (int)((blockIdx.x * (size_t)blockDim.x + threadIdx.x) >> 6);
    if (gw >= N) return;
    const int lane = threadIdx.x & 63;
    const int f8 = lane & 7, e8 = lane >> 3;
    const int s = row_start[gw], c = cnt[gw];

    float acc[8];
#pragma unroll
    for (int k = 0; k < 8; k++) acc[k] = 0.f;

    for (int base = 0; base < c; base += 8) {
        int e = base + e8;
        int ec = (e < c) ? e : (c - 1);
        int j = csr[s + ec];
        uint4 u = *(const uint4*)(in + (size_t)j * 64 + f8 * 8);
        float valid = (e < c) ? 1.f : 0.f;
        acc[0] += valid * bfLo(u.x); acc[1] += valid * bfHi(u.x);
        acc[2] += valid * bfLo(u.y); acc[3] += valid * bfHi(u.y);
        acc[4] += valid * bfLo(u.z); acc[5] += valid * bfHi(u.z);
        acc[6] += valid * bfLo(u.w); acc[7] += valid * bfHi(u.w);
    }
    // reduce over edge slots (stride 32, 16, 8 keeps f8 fixed)
#pragma unroll
    for (int off = 32; off >= 8; off >>= 1) {
#pragma unroll
        for (int k = 0; k < 8; k++) acc[k] += __shfl_down(acc[k], off, 64);
    }
    if (e8 == 0) {   // lanes 0..7 hold feature groups
        uint4 su = *(const uint4*)(in + (size_t)gw * 64 + f8 * 8);
        acc[0] += bfLo(su.x); acc[1] += bfHi(su.x);
        acc[2] += bfLo(su.y); acc[3] += bfHi(su.y);
        acc[4] += bfLo(su.z); acc[5] += bfHi(su.z);
        acc[6] += bfLo(su.w); acc[7] += bfHi(su.w);
        float di = dinv[gw];
#pragma unroll
        for (int k = 0; k < 8; k++) {
            float v = di * acc[k];
            if (BIAS) v += bias[f8 * 8 + k];
            if (RELU) v = fmaxf(v, 0.f);
            if (PREMUL) v *= di;
            acc[k] = v;
        }
        uint4 o;
        o.x = pk(acc[0], acc[1]); o.y = pk(acc[2], acc[3]);
        o.z = pk(acc[4], acc[5]); o.w = pk(acc[6], acc[7]);
        *(uint4*)(out + (size_t)gw * 64 + f8 * 8) = o;
    }
}

// ---------------- fused GEMM2 (+bias,relu) + GEMM3: r = dinv * (relu(a2@W2+b2) @ W3) ----
__global__ __launch_bounds__(256, 2) void gemm23_kernel(const ushort* __restrict__ a2,
                                                        const float* __restrict__ W2,
                                                        const float* __restrict__ b2,
                                                        const float* __restrict__ W3,
                                                        const float* __restrict__ dinv,
                                                        float* __restrict__ r, int N) {
    __shared__ float w2s[64 * 256];
    __shared__ float b2s[256];
    __shared__ float w3s[256];
    const int tid = threadIdx.x;
#pragma unroll
    for (int i = 0; i < 16; i++) {
        int f4 = tid + i * 256;
        *(float4*)&w2s[f4 * 4] = *(const float4*)&W2[f4 * 4];
    }
    b2s[tid] = b2[tid];
    w3s[tid] = W3[tid];
    __syncthreads();

    const int lane = tid & 63;
    const int wave = tid >> 6;
    const int nodeBase = blockIdx.x * 64 + wave * 16;

    float4 w3f = *(const float4*)&w3s[lane * 4];
    float4 b2f = *(const float4*)&b2s[lane * 4];

    float acc[16][4];
#pragma unroll
    for (int n = 0; n < 16; n++) {
        acc[n][0] = 0.f; acc[n][1] = 0.f; acc[n][2] = 0.f; acc[n][3] = 0.f;
    }

    for (int k4 = 0; k4 < 64; k4 += 4) {
        float4 wf0 = *(const float4*)&w2s[(k4 + 0) * 256 + lane * 4];
        float4 wf1 = *(const float4*)&w2s[(k4 + 1) * 256 + lane * 4];
        float4 wf2 = *(const float4*)&w2s[(k4 + 2) * 256 + lane * 4];
        float4 wf3 = *(const float4*)&w2s[(k4 + 3) * 256 + lane * 4];
#pragma unroll
        for (int n = 0; n < 16; n++) {
            int gn = nodeBase + n;
            if (gn >= N) gn = N - 1;
            uint2 u = *(const uint2*)(a2 + (size_t)gn * 64 + k4);
            float a0 = bfLo(u.x), a1 = bfHi(u.x), a2v = bfLo(u.y), a3 = bfHi(u.y);
            acc[n][0] = fmaf(a0, wf0.x, acc[n][0]);
            acc[n][1] = fmaf(a0, wf0.y, acc[n][1]);
            acc[n][2] = fmaf(a0, wf0.z, acc[n][2]);
            acc[n][3] = fmaf(a0, wf0.w, acc[n][3]);
            acc[n][0] = fmaf(a1, wf1.x, acc[n][0]);
            acc[n][1] = fmaf(a1, wf1.y, acc[n][1]);
            acc[n][2] = fmaf(a1, wf1.z, acc[n][2]);
            acc[n][3] = fmaf(a1, wf1.w, acc[n][3]);
            acc[n][0] = fmaf(a2v, wf2.x, acc[n][0]);
            acc[n][1] = fmaf(a2v, wf2.y, acc[n][1]);
            acc[n][2] = fmaf(a2v, wf2.z, acc[n][2]);
            acc[n][3] = fmaf(a2v, wf2.w, acc[n][3]);
            acc[n][0] = fmaf(a3, wf3.x, acc[n][0]);
            acc[n][1] = fmaf(a3, wf3.y, acc[n][1]);
            acc[n][2] = fmaf(a3, wf3.z, acc[n][2]);
            acc[n][3] = fmaf(a3, wf3.w, acc[n][3]);
        }
    }

#pragma unroll
    for (int n = 0; n < 16; n++) {
        float r0 = fmaxf(acc[n][0] + b2f.x, 0.f);
        float r1 = fmaxf(acc[n][1] + b2f.y, 0.f);
        float r2 = fmaxf(acc[n][2] + b2f.z, 0.f);
        float r3 = fmaxf(acc[n][3] + b2f.w, 0.f);
        float p = r0 * w3f.x + r1 * w3f.y + r2 * w3f.z + r3 * w3f.w;
#pragma unroll
        for (int off = 32; off > 0; off >>= 1) p += __shfl_down(p, off, 64);
        int gn = nodeBase + n;
        if (lane == 0 && gn < N) r[gn] = dinv[gn] * p;
    }
}

// ---------------- loss: wave per node, lane = edge; block reduce; 1 atomic/block -------
__global__ void loss_kernel(const float* __restrict__ r, const float* __restrict__ dinv,
                            const int* __restrict__ row_start, const int* __restrict__ cnt,
                            const int* __restrict__ csr, const float* __restrict__ y,
                            const float* __restrict__ b3, float* __restrict__ out,
                            int N, float invN) {
    const int lane = threadIdx.x & 63, wave = threadIdx.x >> 6;
    int gw = (int)((blockIdx.x * (size_t)blockDim.x + threadIdx.x) >> 6);
    float loss = 0.f;
    if (gw < N) {
        int s = row_start[gw], c = cnt[gw];
        float sum = 0.f;
        for (int base = 0; base < c; base += 64) {
            int e = base + lane;
            if (e < c) sum += r[csr[s + e]];
        }
#pragma unroll
        for (int off = 32; off > 0; off >>= 1) sum += __shfl_down(sum, off, 64);
        if (lane == 0) {
            float z = dinv[gw] * (sum + r[gw]) + b3[0];
            float yv = y[gw];
            float L = log1pf(expf(-fabsf(z)));
            float spz  = fmaxf(z, 0.f) + L;
            float spnz = fmaxf(-z, 0.f) + L;
            loss = yv * spnz + (1.f - yv) * spz;
        }
    }
    __shared__ float red[4];
    if (lane == 0) red[wave] = loss;
    __syncthreads();
    if (threadIdx.x == 0)
        atomicAdd(out, (red[0] + red[1] + red[2] + red[3]) * invN);
}

// ---------------- launch ----------------
extern "C" void kernel_launch(void* const* d_in, const int* in_sizes, int n_in,
                              void* d_out, int out_size, void* d_ws, size_t ws_size,
                              hipStream_t stream) {
    const float* x  = (const float*)d_in[0];
    const int*   ei = (const int*)d_in[1];
    const float* y  = (const float*)d_in[2];
    const float* W1 = (const float*)d_in[3];
    const float* b1 = (const float*)d_in[4];
    const float* W2 = (const float*)d_in[5];
    const float* b2 = (const float*)d_in[6];
    const float* W3 = (const float*)d_in[7];
    const float* b3 = (const float*)d_in[8];

    const int N = in_sizes[2];
    const int E = in_sizes[1] / 2;
    const int* src  = ei;
    const int* dstp = ei + E;

    char* w = (char*)d_ws;
    int*    cnt       = (int*)w;    w += (size_t)N * 4;
    int*    cursor    = (int*)w;    w += (size_t)N * 4;
    int*    total     = (int*)w;    w += 16;
    int*    row_start = (int*)w;    w += (size_t)N * 4;
    float*  dinv      = (float*)w;  w += (size_t)N * 4;
    int*    csr       = (int*)w;    w += (size_t)E * 4;
    ushort* wt_hi     = (ushort*)w; w += (size_t)64 * 512 * 2;
    ushort* wt_lo     = (ushort*)w; w += (size_t)64 * 512 * 2;
    ushort* pbuf      = (ushort*)w; w += (size_t)N * 64 * 2;   // p, later a2
    ushort* qbuf      = (ushort*)w; w += (size_t)N * 64 * 2;   // q
    float*  rbuf      = (float*)w;  w += (size_t)N * 4;        // r = dinv*t

    hipMemsetAsync(cnt, 0, (size_t)N * 8 + 16, stream);
    hipMemsetAsync(d_out, 0, sizeof(float), stream);

    const int tb = 256;
    wsplit_kernel<<<(64 * 512 + tb - 1) / tb, tb, 0, stream>>>(W1, wt_hi, wt_lo);
    hist_kernel<<<(E + tb - 1) / tb, tb, 0, stream>>>(dstp, E, cnt);
    alloc_kernel<<<(N + tb - 1) / tb, tb, 0, stream>>>(cnt, row_start, dinv, total, N);
    scatter_kernel<<<(E + tb - 1) / tb, tb, 0, stream>>>(src, dstp, E, row_start, cursor, csr);

    // layer 1: p = dinv * (x @ W1) as bf16
    gemm1_kernel<<<(N + 127) / 128, 256, 0, stream>>>(x, wt_hi, wt_lo, dinv, pbuf, N);
    // q = dinv * relu(dinv * (p_self + sum p_nbr) + b1)
    agg64bf_kernel<1, 1, 1><<<(N + 3) / 4, 256, 0, stream>>>(pbuf, qbuf, row_start, cnt, csr, dinv, b1, N);
    // a2 = dinv * (q_self + sum q_nbr)
    agg64bf_kernel<0, 0, 0><<<(N + 3) / 4, 256, 0, stream>>>(qbuf, pbuf, row_start, cnt, csr, dinv, nullptr, N);

    // layers 2+3 fused: r = dinv * (relu(a2 @ W2 + b2) @ W3)
    gemm23_kernel<<<(N + 63) / 64, 256, 0, stream>>>(pbuf, W2, b2, W3, dinv, rbuf, N);

    // layer 3 aggregation (scalar, premultiplied) + BCE + mean
    loss_kernel<<<(N + 3) / 4, 256, 0, stream>>>(rbuf, dinv, row_start, cnt, csr, y, b3,
                                                 (float*)d_out, N, 1.0f / N);
}

// Round 6
// 739.795 us; speedup vs baseline: 1.3619x; 1.3619x over previous
//
#include <hip/hip_runtime.h>
#include <math.h>

typedef __attribute__((ext_vector_type(8))) short s16x8;   // 8 bf16 (4 VGPRs)
typedef __attribute__((ext_vector_type(4))) float f32x4;

__device__ inline ushort f2bf(float f) {
    union { float f; unsigned u; } v; v.f = f;
    unsigned r = v.u + 0x7FFF + ((v.u >> 16) & 1);   // RTN-even
    return (ushort)(r >> 16);
}
__device__ inline float bf2f(ushort h) {
    union { unsigned u; float f; } v; v.u = ((unsigned)h) << 16;
    return v.f;
}
__device__ inline float bfLo(unsigned u) {
    union { unsigned x; float f; } v; v.x = u << 16; return v.f;
}
__device__ inline float bfHi(unsigned u) {
    union { unsigned x; float f; } v; v.x = u & 0xFFFF0000u; return v.f;
}
__device__ inline unsigned pk(float a, float b) {   // pack 2 bf16
    return (unsigned)f2bf(a) | ((unsigned)f2bf(b) << 16);
}

// ---------------- CSR build ----------------

__global__ void hist_kernel(const int* __restrict__ dst, int E, int* __restrict__ cnt) {
    int e = blockIdx.x * blockDim.x + threadIdx.x;
    if (e < E) atomicAdd(&cnt[dst[e]], 1);
}

__global__ void alloc_kernel(const int* __restrict__ cnt, int* __restrict__ row_start,
                             float* __restrict__ dinv, int* __restrict__ total, int N) {
    int i = blockIdx.x * blockDim.x + threadIdx.x;
    int lane = threadIdx.x & 63;
    int c = (i < N) ? cnt[i] : 0;
    int inc = c;
#pragma unroll
    for (int o = 1; o < 64; o <<= 1) {
        int v = __shfl_up(inc, o, 64);
        if (lane >= o) inc += v;
    }
    int wsum = __shfl(inc, 63, 64);
    int base = 0;
    if (lane == 0) base = atomicAdd(total, wsum);
    base = __shfl(base, 0, 64);
    if (i < N) {
        row_start[i] = base + inc - c;
        dinv[i] = rsqrtf((float)(c + 1));
    }
}

__global__ void scatter_kernel(const int* __restrict__ src, const int* __restrict__ dst, int E,
                               const int* __restrict__ row_start, int* __restrict__ cursor,
                               int* __restrict__ csr) {
    int e = blockIdx.x * blockDim.x + threadIdx.x;
    if (e < E) {
        int d = dst[e];
        int p = row_start[d] + atomicAdd(&cursor[d], 1);
        csr[p] = src[e];
    }
}

// ---------------- W1^T hi/lo split precompute: wt[n][k] bf16 ----------------
__global__ void wsplit_kernel(const float* __restrict__ W, ushort* __restrict__ wt_hi,
                              ushort* __restrict__ wt_lo) {
    int idx = blockIdx.x * blockDim.x + threadIdx.x;
    if (idx < 64 * 512) {
        int n = idx & 63, k = idx >> 6;
        float f = W[k * 64 + n];
        ushort h = f2bf(f);
        wt_hi[n * 512 + k] = h;
        wt_lo[n * 512 + k] = f2bf(f - bf2f(h));
    }
}

// ---------------- GEMM1 (MFMA): p = dinv * (x @ W1) as bf16, hi/lo 3-term split ----------
__global__ __launch_bounds__(256, 3) void gemm1_kernel(const float* __restrict__ x,
                                                       const ushort* __restrict__ wt_hi,
                                                       const ushort* __restrict__ wt_lo,
                                                       const float* __restrict__ dinv,
                                                       ushort* __restrict__ out, int N) {
    __shared__ __align__(16) short xs_hi[128 * 64];
    __shared__ __align__(16) short xs_lo[128 * 64];
    __shared__ __align__(16) short ws_hi[64 * 64];
    __shared__ __align__(16) short ws_lo[64 * 64];

    const int tid = threadIdx.x;
    const int nodeBase = blockIdx.x * 128;
    const int wave = tid >> 6, lane = tid & 63;
    const int m16 = lane & 15, quad = lane >> 4;

    f32x4 acc[2][4];
#pragma unroll
    for (int mt = 0; mt < 2; mt++)
#pragma unroll
        for (int nt = 0; nt < 4; nt++) acc[mt][nt] = (f32x4){0.f, 0.f, 0.f, 0.f};

    for (int kc = 0; kc < 512; kc += 64) {
        __syncthreads();
#pragma unroll
        for (int i = 0; i < 4; i++) {
            int f = tid + i * 256;
            int node = f >> 3, g = f & 7;
            int gn = nodeBase + node;
            if (gn >= N) gn = N - 1;
            const float4 a = *(const float4*)(x + (size_t)gn * 512 + kc + g * 8);
            const float4 b = *(const float4*)(x + (size_t)gn * 512 + kc + g * 8 + 4);
            float ff[8] = {a.x, a.y, a.z, a.w, b.x, b.y, b.z, b.w};
            union { ushort u[8]; uint4 v; } H, L;
#pragma unroll
            for (int j = 0; j < 8; j++) {
                ushort h = f2bf(ff[j]);
                H.u[j] = h;
                L.u[j] = f2bf(ff[j] - bf2f(h));
            }
            int gp = (g + node) & 7;
            *(uint4*)&xs_hi[node * 64 + gp * 8] = H.v;
            *(uint4*)&xs_lo[node * 64 + gp * 8] = L.v;
        }
#pragma unroll
        for (int i = 0; i < 2; i++) {
            int f = tid + i * 256;
            int n = f >> 3, g = f & 7;
            int gp = (g + n) & 7;
            *(uint4*)&ws_hi[n * 64 + gp * 8] =
                *(const uint4*)(wt_hi + (size_t)n * 512 + kc + g * 8);
            *(uint4*)&ws_lo[n * 64 + gp * 8] =
                *(const uint4*)(wt_lo + (size_t)n * 512 + kc + g * 8);
        }
        __syncthreads();
#pragma unroll
        for (int ck = 0; ck < 2; ck++) {
            s16x8 Ah[2], Al[2];
#pragma unroll
            for (int mt = 0; mt < 2; mt++) {
                int row = (wave * 2 + mt) * 16 + m16;
                int gp = (ck * 4 + quad + row) & 7;
                Ah[mt] = *(s16x8*)&xs_hi[row * 64 + gp * 8];
                Al[mt] = *(s16x8*)&xs_lo[row * 64 + gp * 8];
            }
#pragma unroll
            for (int nt = 0; nt < 4; nt++) {
                int n = nt * 16 + m16;
                int gp = (ck * 4 + quad + n) & 7;
                s16x8 Bh = *(s16x8*)&ws_hi[n * 64 + gp * 8];
                s16x8 Bl = *(s16x8*)&ws_lo[n * 64 + gp * 8];
#pragma unroll
                for (int mt = 0; mt < 2; mt++) {
                    acc[mt][nt] = __builtin_amdgcn_mfma_f32_16x16x32_bf16(Ah[mt], Bh, acc[mt][nt], 0, 0, 0);
                    acc[mt][nt] = __builtin_amdgcn_mfma_f32_16x16x32_bf16(Ah[mt], Bl, acc[mt][nt], 0, 0, 0);
                    acc[mt][nt] = __builtin_amdgcn_mfma_f32_16x16x32_bf16(Al[mt], Bh, acc[mt][nt], 0, 0, 0);
                }
            }
        }
    }
#pragma unroll
    for (int mt = 0; mt < 2; mt++) {
#pragma unroll
        for (int r = 0; r < 4; r++) {
            int gn = nodeBase + (wave * 2 + mt) * 16 + quad * 4 + r;
            if (gn < N) {
                float di = dinv[gn];
#pragma unroll
                for (int nt = 0; nt < 4; nt++)
                    out[(size_t)gn * 64 + nt * 16 + m16] = f2bf(di * acc[mt][nt][r]);
            }
        }
    }
}

// ---------------- 64-dim CSR aggregation, 8 edges per vmem instruction ----------------
template <int RELU, int BIAS, int PREMUL>
__global__ void agg64bf_kernel(const ushort* __restrict__ in, ushort* __restrict__ out,
                               const int* __restrict__ row_start, const int* __restrict__ cnt,
                               const int* __restrict__ csr, const float* __restrict__ dinv,
                               const float* __restrict__ bias, int N) {
    int gw = (int)((blockIdx.x * (size_t)blockDim.x + threadIdx.x) >> 6);
    if (gw >= N) return;
    const int lane = threadIdx.x & 63;
    const int f8 = lane & 7, e8 = lane >> 3;
    const int s = row_start[gw], c = cnt[gw];

    float acc[8];
#pragma unroll
    for (int k = 0; k < 8; k++) acc[k] = 0.f;

    for (int base = 0; base < c; base += 8) {
        int e = base + e8;
        int ec = (e < c) ? e : (c - 1);
        int j = csr[s + ec];
        uint4 u = *(const uint4*)(in + (size_t)j * 64 + f8 * 8);
        float valid = (e < c) ? 1.f : 0.f;
        acc[0] += valid * bfLo(u.x); acc[1] += valid * bfHi(u.x);
        acc[2] += valid * bfLo(u.y); acc[3] += valid * bfHi(u.y);
        acc[4] += valid * bfLo(u.z); acc[5] += valid * bfHi(u.z);
        acc[6] += valid * bfLo(u.w); acc[7] += valid * bfHi(u.w);
    }
#pragma unroll
    for (int off = 32; off >= 8; off >>= 1) {
#pragma unroll
        for (int k = 0; k < 8; k++) acc[k] += __shfl_down(acc[k], off, 64);
    }
    if (e8 == 0) {
        uint4 su = *(const uint4*)(in + (size_t)gw * 64 + f8 * 8);
        acc[0] += bfLo(su.x); acc[1] += bfHi(su.x);
        acc[2] += bfLo(su.y); acc[3] += bfHi(su.y);
        acc[4] += bfLo(su.z); acc[5] += bfHi(su.z);
        acc[6] += bfLo(su.w); acc[7] += bfHi(su.w);
        float di = dinv[gw];
#pragma unroll
        for (int k = 0; k < 8; k++) {
            float v = di * acc[k];
            if (BIAS) v += bias[f8 * 8 + k];
            if (RELU) v = fmaxf(v, 0.f);
            if (PREMUL) v *= di;
            acc[k] = v;
        }
        uint4 o;
        o.x = pk(acc[0], acc[1]); o.y = pk(acc[2], acc[3]);
        o.z = pk(acc[4], acc[5]); o.w = pk(acc[6], acc[7]);
        *(uint4*)(out + (size_t)gw * 64 + f8 * 8) = o;
    }
}

// ---------------- fused GEMM2 (+bias,relu) + GEMM3: r = dinv * (relu(a2@W2+b2) @ W3) ----
__global__ __launch_bounds__(256, 2) void gemm23_kernel(const ushort* __restrict__ a2,
                                                        const float* __restrict__ W2,
                                                        const float* __restrict__ b2,
                                                        const float* __restrict__ W3,
                                                        const float* __restrict__ dinv,
                                                        float* __restrict__ r, int N) {
    __shared__ float w2s[64 * 256];
    __shared__ float b2s[256];
    __shared__ float w3s[256];
    const int tid = threadIdx.x;
#pragma unroll
    for (int i = 0; i < 16; i++) {
        int f4 = tid + i * 256;
        *(float4*)&w2s[f4 * 4] = *(const float4*)&W2[f4 * 4];
    }
    b2s[tid] = b2[tid];
    w3s[tid] = W3[tid];
    __syncthreads();

    const int lane = tid & 63;
    const int wave = tid >> 6;
    const int nodeBase = blockIdx.x * 64 + wave * 16;

    float4 w3f = *(const float4*)&w3s[lane * 4];
    float4 b2f = *(const float4*)&b2s[lane * 4];

    float acc[16][4];
#pragma unroll
    for (int n = 0; n < 16; n++) {
        acc[n][0] = 0.f; acc[n][1] = 0.f; acc[n][2] = 0.f; acc[n][3] = 0.f;
    }

    for (int k4 = 0; k4 < 64; k4 += 4) {
        float4 wf0 = *(const float4*)&w2s[(k4 + 0) * 256 + lane * 4];
        float4 wf1 = *(const float4*)&w2s[(k4 + 1) * 256 + lane * 4];
        float4 wf2 = *(const float4*)&w2s[(k4 + 2) * 256 + lane * 4];
        float4 wf3 = *(const float4*)&w2s[(k4 + 3) * 256 + lane * 4];
#pragma unroll
        for (int n = 0; n < 16; n++) {
            int gn = nodeBase + n;
            if (gn >= N) gn = N - 1;
            uint2 u = *(const uint2*)(a2 + (size_t)gn * 64 + k4);
            float a0 = bfLo(u.x), a1 = bfHi(u.x), a2v = bfLo(u.y), a3 = bfHi(u.y);
            acc[n][0] = fmaf(a0, wf0.x, acc[n][0]);
            acc[n][1] = fmaf(a0, wf0.y, acc[n][1]);
            acc[n][2] = fmaf(a0, wf0.z, acc[n][2]);
            acc[n][3] = fmaf(a0, wf0.w, acc[n][3]);
            acc[n][0] = fmaf(a1, wf1.x, acc[n][0]);
            acc[n][1] = fmaf(a1, wf1.y, acc[n][1]);
            acc[n][2] = fmaf(a1, wf1.z, acc[n][2]);
            acc[n][3] = fmaf(a1, wf1.w, acc[n][3]);
            acc[n][0] = fmaf(a2v, wf2.x, acc[n][0]);
            acc[n][1] = fmaf(a2v, wf2.y, acc[n][1]);
            acc[n][2] = fmaf(a2v, wf2.z, acc[n][2]);
            acc[n][3] = fmaf(a2v, wf2.w, acc[n][3]);
            acc[n][0] = fmaf(a3, wf3.x, acc[n][0]);
            acc[n][1] = fmaf(a3, wf3.y, acc[n][1]);
            acc[n][2] = fmaf(a3, wf3.z, acc[n][2]);
            acc[n][3] = fmaf(a3, wf3.w, acc[n][3]);
        }
    }

#pragma unroll
    for (int n = 0; n < 16; n++) {
        float r0 = fmaxf(acc[n][0] + b2f.x, 0.f);
        float r1 = fmaxf(acc[n][1] + b2f.y, 0.f);
        float r2 = fmaxf(acc[n][2] + b2f.z, 0.f);
        float r3 = fmaxf(acc[n][3] + b2f.w, 0.f);
        float p = r0 * w3f.x + r1 * w3f.y + r2 * w3f.z + r3 * w3f.w;
#pragma unroll
        for (int off = 32; off > 0; off >>= 1) p += __shfl_down(p, off, 64);
        int gn = nodeBase + n;
        if (lane == 0 && gn < N) r[gn] = dinv[gn] * p;
    }
}

// ---------------- loss: grid-stride wave-per-node; 1 atomic per block (1024 total) ------
__global__ __launch_bounds__(256, 4) void loss_kernel(const float* __restrict__ r,
                                                      const float* __restrict__ dinv,
                                                      const int* __restrict__ row_start,
                                                      const int* __restrict__ cnt,
                                                      const int* __restrict__ csr,
                                                      const float* __restrict__ y,
                                                      const float* __restrict__ b3,
                                                      float* __restrict__ out,
                                                      int N, float invN, int numWaves) {
    const int lane = threadIdx.x & 63, wave = threadIdx.x >> 6;
    const int waveId = blockIdx.x * 4 + wave;
    const float bias3 = b3[0];
    float lossAcc = 0.f;

    for (int gw = waveId; gw < N; gw += numWaves) {
        int s = row_start[gw], c = cnt[gw];
        float sum = 0.f;
        for (int base = 0; base < c; base += 64) {
            int e = base + lane;
            if (e < c) sum += r[csr[s + e]];
        }
#pragma unroll
        for (int off = 32; off > 0; off >>= 1) sum += __shfl_down(sum, off, 64);
        if (lane == 0) {
            float z = dinv[gw] * (sum + r[gw]) + bias3;
            float yv = y[gw];
            float L = log1pf(expf(-fabsf(z)));
            float spz  = fmaxf(z, 0.f) + L;
            float spnz = fmaxf(-z, 0.f) + L;
            lossAcc += yv * spnz + (1.f - yv) * spz;
        }
    }
    __shared__ float red[4];
    if (lane == 0) red[wave] = lossAcc;
    __syncthreads();
    if (threadIdx.x == 0)
        atomicAdd(out, (red[0] + red[1] + red[2] + red[3]) * invN);
}

// ---------------- launch ----------------
extern "C" void kernel_launch(void* const* d_in, const int* in_sizes, int n_in,
                              void* d_out, int out_size, void* d_ws, size_t ws_size,
                              hipStream_t stream) {
    const float* x  = (const float*)d_in[0];
    const int*   ei = (const int*)d_in[1];
    const float* y  = (const float*)d_in[2];
    const float* W1 = (const float*)d_in[3];
    const float* b1 = (const float*)d_in[4];
    const float* W2 = (const float*)d_in[5];
    const float* b2 = (const float*)d_in[6];
    const float* W3 = (const float*)d_in[7];
    const float* b3 = (const float*)d_in[8];

    const int N = in_sizes[2];
    const int E = in_sizes[1] / 2;
    const int* src  = ei;
    const int* dstp = ei + E;

    char* w = (char*)d_ws;
    int*    cnt       = (int*)w;    w += (size_t)N * 4;
    int*    cursor    = (int*)w;    w += (size_t)N * 4;
    int*    total     = (int*)w;    w += 16;
    int*    row_start = (int*)w;    w += (size_t)N * 4;
    float*  dinv      = (float*)w;  w += (size_t)N * 4;
    int*    csr       = (int*)w;    w += (size_t)E * 4;
    ushort* wt_hi     = (ushort*)w; w += (size_t)64 * 512 * 2;
    ushort* wt_lo     = (ushort*)w; w += (size_t)64 * 512 * 2;
    ushort* pbuf      = (ushort*)w; w += (size_t)N * 64 * 2;   // p, later a2
    ushort* qbuf      = (ushort*)w; w += (size_t)N * 64 * 2;   // q
    float*  rbuf      = (float*)w;  w += (size_t)N * 4;        // r = dinv*t

    hipMemsetAsync(cnt, 0, (size_t)N * 8 + 16, stream);
    hipMemsetAsync(d_out, 0, sizeof(float), stream);

    const int tb = 256;
    wsplit_kernel<<<(64 * 512 + tb - 1) / tb, tb, 0, stream>>>(W1, wt_hi, wt_lo);
    hist_kernel<<<(E + tb - 1) / tb, tb, 0, stream>>>(dstp, E, cnt);
    alloc_kernel<<<(N + tb - 1) / tb, tb, 0, stream>>>(cnt, row_start, dinv, total, N);
    scatter_kernel<<<(E + tb - 1) / tb, tb, 0, stream>>>(src, dstp, E, row_start, cursor, csr);

    // layer 1: p = dinv * (x @ W1) as bf16
    gemm1_kernel<<<(N + 127) / 128, 256, 0, stream>>>(x, wt_hi, wt_lo, dinv, pbuf, N);
    // q = dinv * relu(dinv * (p_self + sum p_nbr) + b1)
    agg64bf_kernel<1, 1, 1><<<(N + 3) / 4, 256, 0, stream>>>(pbuf, qbuf, row_start, cnt, csr, dinv, b1, N);
    // a2 = dinv * (q_self + sum q_nbr)
    agg64bf_kernel<0, 0, 0><<<(N + 3) / 4, 256, 0, stream>>>(qbuf, pbuf, row_start, cnt, csr, dinv, nullptr, N);

    // layers 2+3 fused: r = dinv * (relu(a2 @ W2 + b2) @ W3)
    gemm23_kernel<<<(N + 63) / 64, 256, 0, stream>>>(pbuf, W2, b2, W3, dinv, rbuf, N);

    // layer 3 aggregation (scalar, premultiplied) + BCE + mean; 1024 blocks -> 1024 atomics
    const int lossBlocks = 1024;
    loss_kernel<<<lossBlocks, 256, 0, stream>>>(rbuf, dinv, row_start, cnt, csr, y, b3,
                                                (float*)d_out, N, 1.0f / N, lossBlocks * 4);
}